// Round 5
// baseline (214.326 us; speedup 1.0000x reference)
//
#include <hip/hip_runtime.h>
#include <math.h>

// GenSP: SSN superpixels, x(1,64,384,384), stoken=16.
// S=576 superpixels (24x24 grid of 16x16 px blocks), C=64, P=147456, N_ITER=3.
// f64 label chain (R1/R3/R4 bit-matched np f64 ref, absmax 0.0).
// R5: distance via |c|^2 - 2 x.c expansion (Sum x^2 cancels in softmax/argmax),
// centroids via wave-uniform s_load (scalar pipe), zero-redundancy thread maps,
// 128px chunks (grid 1152), <=2-way LDS patterns throughout.

#define NC   64
#define IMW  384
#define HWP  (384*384)
#define NSH  24
#define NSW  24
#define NS   (NSH*NSW)
#define NBG  (NS*2)       // 1152 chunk-blocks (2 x 128px per superpixel block)
#define NCP  (NS*4)       // cent_init partial blocks (4 x 64px)
#define XR   65           // xb row stride (floats): (65p+c)%32=(p+c)%32 -> 2-way

// ---- K1a: per-chunk partial sums for initial centroids (R4, validated) ----
__global__ __launch_bounds__(256) void k_cent_part(const float* __restrict__ x,
                                                   double* __restrict__ centp) {
    int bg = blockIdx.x, b = bg >> 2, g = bg & 3;
    int by = b / NSW, bx = b % NSW;
    int t = threadIdx.x, q = t >> 2, r = t & 3;
    const float* gp = x + (size_t)q * HWP + (size_t)(by * 16 + g * 4) * IMW + bx * 16 + r * 4;
    double s = 0.0;
    #pragma unroll
    for (int j = 0; j < 4; ++j) {
        float4 v = *(const float4*)(gp + (size_t)j * IMW);
        s += (double)v.x; s += (double)v.y; s += (double)v.z; s += (double)v.w;
    }
    s += __shfl_xor(s, 1, 64);
    s += __shfl_xor(s, 2, 64);
    if (r == 0) centp[(size_t)bg * NC + q] = s;
}

__global__ __launch_bounds__(64) void k_cent_red(const double* __restrict__ centp,
                                                 double* __restrict__ cent) {
    int s = blockIdx.x, c = threadIdx.x;
    double v = centp[(size_t)(s * 4 + 0) * NC + c] + centp[(size_t)(s * 4 + 1) * NC + c]
             + centp[(size_t)(s * 4 + 2) * NC + c] + centp[(size_t)(s * 4 + 3) * NC + c];
    cent[s * NC + c] = v * (1.0 / 256.0);
}

// ---- shared: stage 128px x 64ch chunk into LDS + cnorm ---------------------
__device__ __forceinline__ void stage128(const float* __restrict__ x,
        const double* __restrict__ cent, int by, int bx, int g, int t,
        float* __restrict__ xb, double* __restrict__ cnorm) {
    int q = t >> 2, r = t & 3;
    const float* gp = x + (size_t)q * HWP + (size_t)(by * 16 + g * 8) * IMW + bx * 16 + r * 4;
    #pragma unroll
    for (int j = 0; j < 8; ++j) {
        float4 v = *(const float4*)(gp + (size_t)j * IMW);
        int p0 = j * 16 + r * 4;
        xb[(p0 + 0) * XR + q] = v.x;
        xb[(p0 + 1) * XR + q] = v.y;
        xb[(p0 + 2) * XR + q] = v.z;
        xb[(p0 + 3) * XR + q] = v.w;
    }
    if (t < 9) {
        int cy = by + t / 3 - 1, cx = bx + t % 3 - 1;
        double s = 0.0;
        if (cy >= 0 && cy < NSH && cx >= 0 && cx < NSW) {
            const double* cr = cent + (size_t)(cy * NSW + cx) * NC;
            for (int c = 0; c < NC; ++c) s = fma(cr[c], cr[c], s);
        }
        cnorm[t] = s;
    }
}

// phase B core: thread (p = t&127, kh = t>>7); 5 (or 4) k's, 64-ch dot via s_load
__device__ __forceinline__ void dist_expand(const float* __restrict__ xb,
        const double* __restrict__ cent, const double* __restrict__ cnorm,
        double* __restrict__ dbuf, int by, int bx, int t) {
    int p = t & 127, kh = t >> 7;
    int kbase = kh * 5;                  // kh=0: k=0..4 (5), kh=1: k=5..8 (4)
    int nk = kh ? 4 : 5;
    const double* crow[5]; bool kv[5];
    #pragma unroll
    for (int j = 0; j < 5; ++j) {
        int k = kbase + j; if (k > 8) k = 8;        // dup pad, ignored on write
        int cy = by + k / 3 - 1, cx = bx + k % 3 - 1;
        bool v = (cy >= 0) && (cy < NSH) && (cx >= 0) && (cx < NSW);
        kv[j] = v;
        crow[j] = cent + (size_t)(v ? (cy * NSW + cx) : 0) * NC;
    }
    const float* xr = &xb[p * XR];
    double dot[5] = {0, 0, 0, 0, 0};
    for (int c = 0; c < NC; ++c) {
        double xv = (double)xr[c];
        #pragma unroll
        for (int j = 0; j < 5; ++j) dot[j] = fma(xv, crow[j][c], dot[j]);
    }
    for (int j = 0; j < nk; ++j) {
        int k = kbase + j;
        dbuf[k * 128 + p] = kv[j] ? fma(dot[j], -2.0, cnorm[k]) : 1e300;
    }
}

__device__ __forceinline__ void valid9(int by, int bx, bool* vld) {
    #pragma unroll
    for (int k = 0; k < 9; ++k) {
        int cy = by + k / 3 - 1, cx = bx + k % 3 - 1;
        vld[k] = (cy >= 0) && (cy < NSH) && (cx >= 0) && (cx < NSW);
    }
}

// ---- K2: soft iteration ----------------------------------------------------
__global__ __launch_bounds__(256, 3) void k_iter(const float* __restrict__ x,
        const double* __restrict__ cent,
        double* __restrict__ bnum, double* __restrict__ bden) {
    int bg = blockIdx.x, b = bg >> 1, g = bg & 1;
    int by = b / NSW, bx = b % NSW;
    int t = threadIdx.x;
    __shared__ float  xb[128 * XR];      // 33280 B
    __shared__ double dbuf[9 * 128];     // 9216 B: d, then aff in-place
    __shared__ double cnorm[9];

    stage128(x, cent, by, bx, g, t, xb, cnorm);
    __syncthreads();
    dist_expand(xb, cent, cnorm, dbuf, by, bx, t);
    __syncthreads();

    if (t < 128) {                       // softmax per pixel, all 9 k in-thread
        bool vld[9]; valid9(by, bx, vld);
        double dd[9];
        #pragma unroll
        for (int k = 0; k < 9; ++k) dd[k] = dbuf[k * 128 + t];
        double m = -1e300;
        #pragma unroll
        for (int k = 0; k < 9; ++k) if (vld[k]) m = fmax(m, -dd[k]);
        double e[9], ss = 0.0;
        #pragma unroll
        for (int k = 0; k < 9; ++k) { e[k] = vld[k] ? exp(-dd[k] - m) : 0.0; ss += e[k]; }
        double inv = 1.0 / ss;
        #pragma unroll
        for (int k = 0; k < 9; ++k) { e[k] *= inv; dbuf[k * 128 + t] = e[k]; }
        int w2 = t >> 6, lane = t & 63;
        #pragma unroll
        for (int k = 0; k < 9; ++k) {    // den partials per (chunk, half, k)
            double dn = e[k];
            #pragma unroll
            for (int off = 32; off >= 1; off >>= 1) dn += __shfl_down(dn, off, 64);
            if (lane == 0) bden[((size_t)bg * 2 + w2) * 9 + k] = dn;
        }
    }
    __syncthreads();

    // C: thread (c = t&63, kq = t>>6) -> k in {kq, kq+4, 8 if kq==0}
    int c = t & 63, kq = t >> 6;
    double a0 = 0, a1 = 0, a2 = 0;
    for (int pp = 0; pp < 128; ++pp) {
        double xv = (double)xb[pp * XR + c];
        a0 = fma(dbuf[kq * 128 + pp], xv, a0);
        a1 = fma(dbuf[(kq + 4) * 128 + pp], xv, a1);
        if (kq == 0) a2 = fma(dbuf[8 * 128 + pp], xv, a2);
    }
    bnum[((size_t)bg * 9 + kq) * NC + c] = a0;
    bnum[((size_t)bg * 9 + kq + 4) * NC + c] = a1;
    if (kq == 0) bnum[((size_t)bg * 9 + 8) * NC + c] = a2;
}

// ---- K3: centroid update ---------------------------------------------------
__global__ __launch_bounds__(64) void k_gather_cent(const double* __restrict__ bnum,
                                                    const double* __restrict__ bden,
                                                    double* __restrict__ cent) {
    int s = blockIdx.x, c = threadIdx.x;
    int sy = s / NSW, sx = s % NSW;
    double num = 0.0, den = 0.0;
    #pragma unroll
    for (int k = 0; k < 9; ++k) {
        int by2 = sy - (k / 3 - 1), bx2 = sx - (k % 3 - 1);
        if (by2 >= 0 && by2 < NSH && bx2 >= 0 && bx2 < NSW) {
            int b2 = by2 * NSW + bx2;
            #pragma unroll
            for (int g = 0; g < 2; ++g) {
                int bg = b2 * 2 + g;
                num += bnum[((size_t)bg * 9 + k) * NC + c];
                den += bden[((size_t)bg * 2 + 0) * 9 + k]
                     + bden[((size_t)bg * 2 + 1) * 9 + k];
            }
        }
    }
    cent[s * NC + c] = num / (den + 1e-16);
}

// ---- K4: final argmin + hard-label partial sums ----------------------------
__global__ __launch_bounds__(256, 3) void k_final(const float* __restrict__ x,
        const double* __restrict__ cent, int* __restrict__ labels,
        double* __restrict__ bnum, double* __restrict__ bden) {
    int bg = blockIdx.x, b = bg >> 1, g = bg & 1;
    int by = b / NSW, bx = b % NSW;
    int t = threadIdx.x;
    __shared__ float  xb[128 * XR];
    __shared__ double dbuf[9 * 128];
    __shared__ double cnorm[9];
    __shared__ int    ibk[128];

    stage128(x, cent, by, bx, g, t, xb, cnorm);
    __syncthreads();
    dist_expand(xb, cent, cnorm, dbuf, by, bx, t);
    __syncthreads();

    if (t < 128) {
        bool vld[9]; valid9(by, bx, vld);
        double bestd = 1e300; int bk = 0;
        #pragma unroll
        for (int k = 0; k < 9; ++k) {
            double dv = dbuf[k * 128 + t];
            if (vld[k] && dv < bestd) { bestd = dv; bk = k; }   // first-wins
        }
        ibk[t] = bk;
        int prow = t >> 4, pcol = t & 15;
        labels[(size_t)(by * 16 + g * 8 + prow) * IMW + bx * 16 + pcol] =
            (by + bk / 3 - 1) * NSW + (bx + bk % 3 - 1);
        int w2 = t >> 6, lane = t & 63;
        #pragma unroll
        for (int k = 0; k < 9; ++k) {
            int cnt = (bk == k);
            #pragma unroll
            for (int off = 32; off >= 1; off >>= 1) cnt += __shfl_down(cnt, off, 64);
            if (lane == 0) bden[((size_t)bg * 2 + w2) * 9 + k] = (double)cnt;
        }
    }
    __syncthreads();

    int c = t & 63, kq = t >> 6;
    double a0 = 0, a1 = 0, a2 = 0;
    for (int pp = 0; pp < 128; ++pp) {
        int bkp = ibk[pp];
        double xv = (double)xb[pp * XR + c];
        a0 += (bkp == kq) ? xv : 0.0;
        a1 += (bkp == kq + 4) ? xv : 0.0;
        if (kq == 0) a2 += (bkp == 8) ? xv : 0.0;
    }
    bnum[((size_t)bg * 9 + kq) * NC + c] = a0;
    bnum[((size_t)bg * 9 + kq + 4) * NC + c] = a1;
    if (kq == 0) bnum[((size_t)bg * 9 + 8) * NC + c] = a2;
}

// ---- K5: paint means -------------------------------------------------------
__global__ __launch_bounds__(64) void k_means_(const double* __restrict__ bnum,
                                               const double* __restrict__ bden,
                                               float* __restrict__ means) {
    int s = blockIdx.x, c = threadIdx.x;
    int sy = s / NSW, sx = s % NSW;
    double num = 0.0, den = 0.0;
    #pragma unroll
    for (int k = 0; k < 9; ++k) {
        int by2 = sy - (k / 3 - 1), bx2 = sx - (k % 3 - 1);
        if (by2 >= 0 && by2 < NSH && bx2 >= 0 && bx2 < NSW) {
            int b2 = by2 * NSW + bx2;
            #pragma unroll
            for (int g = 0; g < 2; ++g) {
                int bg = b2 * 2 + g;
                num += bnum[((size_t)bg * 9 + k) * NC + c];
                den += bden[((size_t)bg * 2 + 0) * 9 + k]
                     + bden[((size_t)bg * 2 + 1) * 9 + k];
            }
        }
    }
    means[s * NC + c] = (float)(num / fmax(den, 1.0));
}

__global__ __launch_bounds__(256) void k_paint(const int* __restrict__ labels,
                                               const float* __restrict__ means,
                                               float* __restrict__ out) {
    int p0 = (blockIdx.x * 256 + threadIdx.x) * 4;
    int4 lb = *(const int4*)&labels[p0];
    int c0 = blockIdx.y * 4;
    #pragma unroll
    for (int j = 0; j < 4; ++j) {
        int c = c0 + j;
        float4 o;
        o.x = means[lb.x * NC + c];
        o.y = means[lb.y * NC + c];
        o.z = means[lb.z * NC + c];
        o.w = means[lb.w * NC + c];
        *(float4*)&out[(size_t)c * HWP + p0] = o;
    }
}

extern "C" void kernel_launch(void* const* d_in, const int* in_sizes, int n_in,
                              void* d_out, int out_size, void* d_ws, size_t ws_size,
                              hipStream_t stream) {
    const float* x = (const float*)d_in[0];
    float* out = (float*)d_out;
    char* ws = (char*)d_ws;
    char* od = (char*)d_out;

    constexpr size_t CENTP_B = (size_t)NCP * NC * 8;      // 1179648
    constexpr size_t CENT_B  = (size_t)NS * NC * 8;       // 294912 (x2)
    constexpr size_t BNUM_B  = (size_t)NBG * 9 * NC * 8;  // 5308416
    constexpr size_t BDEN_B  = (size_t)NBG * 2 * 9 * 8;   // 165888
    constexpr size_t LAB_B   = (size_t)HWP * 4;           // 589824
    constexpr size_t MEANS_B = (size_t)NS * NC * 4;       // 147456
    constexpr size_t T_PAINT = LAB_B + MEANS_B;
    constexpr size_t T_CENT  = T_PAINT + 2 * CENT_B;
    constexpr size_t T_ALL   = T_CENT + CENTP_B + BNUM_B + BDEN_B;

    int* labels = (int*)ws;
    float* means = (float*)(ws + LAB_B);
    double *centA, *centB, *centp, *bnum, *bden;
    if (ws_size >= T_ALL) {
        centA = (double*)(ws + T_PAINT);
        centB = (double*)(ws + T_PAINT + CENT_B);
        centp = (double*)(ws + T_CENT);
        bnum  = (double*)(ws + T_CENT + CENTP_B);
        bden  = (double*)(ws + T_CENT + CENTP_B + BNUM_B);
    } else if (ws_size >= T_CENT) {
        centA = (double*)(ws + T_PAINT);
        centB = (double*)(ws + T_PAINT + CENT_B);
        centp = (double*)od;
        bnum  = (double*)(od + CENTP_B);
        bden  = (double*)(od + CENTP_B + BNUM_B);
    } else {
        centp = (double*)od;
        bnum  = (double*)(od + CENTP_B);
        bden  = (double*)(od + CENTP_B + BNUM_B);
        centA = (double*)(od + CENTP_B + BNUM_B + BDEN_B);
        centB = (double*)(od + CENTP_B + BNUM_B + BDEN_B + CENT_B);
    }
    // all d_out-resident scratch is consumed before k_paint overwrites d_out

    k_cent_part<<<NCP, 256, 0, stream>>>(x, centp);
    k_cent_red<<<NS, 64, 0, stream>>>(centp, centA);
    k_iter<<<NBG, 256, 0, stream>>>(x, centA, bnum, bden);
    k_gather_cent<<<NS, 64, 0, stream>>>(bnum, bden, centB);
    k_iter<<<NBG, 256, 0, stream>>>(x, centB, bnum, bden);
    k_gather_cent<<<NS, 64, 0, stream>>>(bnum, bden, centA);
    k_final<<<NBG, 256, 0, stream>>>(x, centA, labels, bnum, bden);
    k_means_<<<NS, 64, 0, stream>>>(bnum, bden, means);
    k_paint<<<dim3(HWP / 1024, NC / 4), 256, 0, stream>>>(labels, means, out);
}

// Round 7
// 135.961 us; speedup vs baseline: 1.5764x; 1.5764x over previous
//
#include <hip/hip_runtime.h>
#include <math.h>

// GenSP: SSN superpixels, x(1,64,384,384), stoken=16.
// S=576 superpixels (24x24 grid of 16x16 px blocks), C=64, P=147456, N_ITER=3.
// f64 label chain (R1/R3/R4/R5 all bit-matched np f64 ref, absmax 0.0).
// R6: thread=pixel distance with SCALAR-PIPE centroid loads (addresses derive
// from blockIdx+loop counters only -> s_load; R5 failed because kh=t>>7
// tainted uniformity). x never staged in LDS (coalesced b32 + L1-hot float4
// re-read). LDS holds only aff (9x64 f64, uniform-broadcast reads).
// 64-thread blocks, grid 2304 (9 blocks/CU).

#define NC   64
#define IMW  384
#define HWP  (384*384)
#define NSH  24
#define NSW  24
#define NS   (NSH*NSW)
#define NBG  (NS*4)       // 2304 chunk-blocks (4 x 64px per superpixel block)

// ---- K1a: per-chunk partial sums for initial centroids (R4, validated) ----
__global__ __launch_bounds__(256) void k_cent_part(const float* __restrict__ x,
                                                   double* __restrict__ centp) {
    int bg = blockIdx.x, b = bg >> 2, g = bg & 3;
    int by = b / NSW, bx = b % NSW;
    int t = threadIdx.x, q = t >> 2, r = t & 3;
    const float* gp = x + (size_t)q * HWP + (size_t)(by * 16 + g * 4) * IMW + bx * 16 + r * 4;
    double s = 0.0;
    #pragma unroll
    for (int j = 0; j < 4; ++j) {
        float4 v = *(const float4*)(gp + (size_t)j * IMW);
        s += (double)v.x; s += (double)v.y; s += (double)v.z; s += (double)v.w;
    }
    s += __shfl_xor(s, 1, 64);
    s += __shfl_xor(s, 2, 64);
    if (r == 0) centp[(size_t)bg * NC + q] = s;
}

// ---- K1b: reduce 4 chunk partials -> initial cent + cnorm -----------------
__global__ __launch_bounds__(64) void k_cent_red(const double* __restrict__ centp,
                                                 double* __restrict__ cent,
                                                 double* __restrict__ cnorm) {
    int s = blockIdx.x, c = threadIdx.x;
    double v = centp[(size_t)(s * 4 + 0) * NC + c] + centp[(size_t)(s * 4 + 1) * NC + c]
             + centp[(size_t)(s * 4 + 2) * NC + c] + centp[(size_t)(s * 4 + 3) * NC + c];
    v *= (1.0 / 256.0);
    cent[s * NC + c] = v;
    double n2 = v * v;
    #pragma unroll
    for (int off = 32; off >= 1; off >>= 1) n2 += __shfl_down(n2, off, 64);
    if (c == 0) cnorm[s] = n2;
}

// ---- K2: soft iteration: dist(scalar-pipe cent) + softmax + dot -----------
__global__ __launch_bounds__(64) void k_iter(const float* __restrict__ x,
        const double* __restrict__ cent, const double* __restrict__ cnorm,
        double* __restrict__ bnum, double* __restrict__ bden) {
    int bg = blockIdx.x, b = bg >> 2, g = bg & 3;
    int by = b / NSW, bx = b % NSW;
    int t = threadIdx.x;
    __shared__ double aff[9][66];        // [k][pixel], 4.75 KB

    int cand[9]; bool vld[9];
    #pragma unroll
    for (int k = 0; k < 9; ++k) {        // pure blockIdx math -> SGPR
        int cy = by + k / 3 - 1, cx = bx + k % 3 - 1;
        vld[k] = (cy >= 0) && (cy < NSH) && (cx >= 0) && (cx < NSW);
        cand[k] = vld[k] ? (cy * NSW + cx) : 0;
    }

    // distance: thread = pixel; cent[cand[k]*NC+c] is uniform -> s_load
    const float* xp = x + (size_t)(by * 16 + g * 4 + (t >> 4)) * IMW + bx * 16 + (t & 15);
    double dot[9] = {0, 0, 0, 0, 0, 0, 0, 0, 0};
    #pragma unroll 4
    for (int c = 0; c < NC; ++c) {
        double xv = (double)xp[(size_t)c * HWP];
        #pragma unroll
        for (int k = 0; k < 9; ++k)
            dot[k] = fma(xv, cent[(size_t)cand[k] * NC + c], dot[k]);
    }
    double d[9], m = -1e300;
    #pragma unroll
    for (int k = 0; k < 9; ++k) {
        d[k] = fma(dot[k], -2.0, cnorm[cand[k]]);
        if (vld[k]) m = fmax(m, -d[k]);
    }
    double e[9], ss = 0.0;
    #pragma unroll
    for (int k = 0; k < 9; ++k) { e[k] = vld[k] ? exp(-d[k] - m) : 0.0; ss += e[k]; }
    double inv = 1.0 / ss;
    #pragma unroll
    for (int k = 0; k < 9; ++k) { e[k] *= inv; aff[k][t] = e[k]; }

    #pragma unroll
    for (int k = 0; k < 9; ++k) {        // den per (chunk,k), R5 reduce pattern
        double dn = e[k];
        #pragma unroll
        for (int off = 32; off >= 1; off >>= 1) dn += __shfl_down(dn, off, 64);
        if (t == 0) bden[(size_t)bg * 9 + k] = dn;
    }
    __syncthreads();

    // dot phase: lane = channel; x re-read as float4 (L1-hot), aff broadcast
    int c = t;
    double acc[9] = {0, 0, 0, 0, 0, 0, 0, 0, 0};
    const float* xq = x + (size_t)c * HWP + (size_t)(by * 16 + g * 4) * IMW + bx * 16;
    for (int r = 0; r < 4; ++r) {
        #pragma unroll
        for (int q = 0; q < 4; ++q) {
            float4 xv = *(const float4*)(xq + (size_t)r * IMW + q * 4);
            int pp = r * 16 + q * 4;
            #pragma unroll
            for (int k = 0; k < 9; ++k) {
                acc[k] = fma(aff[k][pp + 0], (double)xv.x, acc[k]);
                acc[k] = fma(aff[k][pp + 1], (double)xv.y, acc[k]);
                acc[k] = fma(aff[k][pp + 2], (double)xv.z, acc[k]);
                acc[k] = fma(aff[k][pp + 3], (double)xv.w, acc[k]);
            }
        }
    }
    #pragma unroll
    for (int k = 0; k < 9; ++k) bnum[((size_t)bg * 9 + k) * NC + c] = acc[k];
}

// ---- K3: centroid update: gather 9k x 4g partials -> cent + cnorm ---------
__global__ __launch_bounds__(64) void k_gather_cent(const double* __restrict__ bnum,
                                                    const double* __restrict__ bden,
                                                    double* __restrict__ cent,
                                                    double* __restrict__ cnorm) {
    int s = blockIdx.x, c = threadIdx.x;
    int sy = s / NSW, sx = s % NSW;
    double num = 0.0, den = 0.0;
    #pragma unroll
    for (int k = 0; k < 9; ++k) {
        int by2 = sy - (k / 3 - 1), bx2 = sx - (k % 3 - 1);
        if (by2 >= 0 && by2 < NSH && bx2 >= 0 && bx2 < NSW) {
            int b2 = by2 * NSW + bx2;
            #pragma unroll
            for (int g = 0; g < 4; ++g) {
                int bg = b2 * 4 + g;
                num += bnum[((size_t)bg * 9 + k) * NC + c];
                den += bden[(size_t)bg * 9 + k];
            }
        }
    }
    double v = num / (den + 1e-16);
    cent[s * NC + c] = v;
    double n2 = v * v;
    #pragma unroll
    for (int off = 32; off >= 1; off >>= 1) n2 += __shfl_down(n2, off, 64);
    if (c == 0) cnorm[s] = n2;
}

// ---- K4: final: argmin labels + hard-label (indicator) partial sums -------
__global__ __launch_bounds__(64) void k_final(const float* __restrict__ x,
        const double* __restrict__ cent, const double* __restrict__ cnorm,
        int* __restrict__ labels,
        double* __restrict__ bnum, double* __restrict__ bden) {
    int bg = blockIdx.x, b = bg >> 2, g = bg & 3;
    int by = b / NSW, bx = b % NSW;
    int t = threadIdx.x;
    __shared__ double aff[9][66];

    int cand[9]; bool vld[9];
    #pragma unroll
    for (int k = 0; k < 9; ++k) {
        int cy = by + k / 3 - 1, cx = bx + k % 3 - 1;
        vld[k] = (cy >= 0) && (cy < NSH) && (cx >= 0) && (cx < NSW);
        cand[k] = vld[k] ? (cy * NSW + cx) : 0;
    }

    const float* xp = x + (size_t)(by * 16 + g * 4 + (t >> 4)) * IMW + bx * 16 + (t & 15);
    double dot[9] = {0, 0, 0, 0, 0, 0, 0, 0, 0};
    #pragma unroll 4
    for (int c = 0; c < NC; ++c) {
        double xv = (double)xp[(size_t)c * HWP];
        #pragma unroll
        for (int k = 0; k < 9; ++k)
            dot[k] = fma(xv, cent[(size_t)cand[k] * NC + c], dot[k]);
    }
    double bestd = 1e300; int bk = 0;
    #pragma unroll
    for (int k = 0; k < 9; ++k) {
        double dv = fma(dot[k], -2.0, cnorm[cand[k]]);
        if (vld[k] && dv < bestd) { bestd = dv; bk = k; }   // first-wins
    }
    labels[(size_t)(by * 16 + g * 4 + (t >> 4)) * IMW + bx * 16 + (t & 15)] =
        (by + bk / 3 - 1) * NSW + (bx + bk % 3 - 1);
    #pragma unroll
    for (int k = 0; k < 9; ++k) aff[k][t] = (bk == k) ? 1.0 : 0.0;

    #pragma unroll
    for (int k = 0; k < 9; ++k) {        // counts per (chunk,k)
        int cnt = (bk == k);
        #pragma unroll
        for (int off = 32; off >= 1; off >>= 1) cnt += __shfl_down(cnt, off, 64);
        if (t == 0) bden[(size_t)bg * 9 + k] = (double)cnt;
    }
    __syncthreads();

    int c = t;
    double acc[9] = {0, 0, 0, 0, 0, 0, 0, 0, 0};
    const float* xq = x + (size_t)c * HWP + (size_t)(by * 16 + g * 4) * IMW + bx * 16;
    for (int r = 0; r < 4; ++r) {
        #pragma unroll
        for (int q = 0; q < 4; ++q) {
            float4 xv = *(const float4*)(xq + (size_t)r * IMW + q * 4);
            int pp = r * 16 + q * 4;
            #pragma unroll
            for (int k = 0; k < 9; ++k) {
                acc[k] = fma(aff[k][pp + 0], (double)xv.x, acc[k]);
                acc[k] = fma(aff[k][pp + 1], (double)xv.y, acc[k]);
                acc[k] = fma(aff[k][pp + 2], (double)xv.z, acc[k]);
                acc[k] = fma(aff[k][pp + 3], (double)xv.w, acc[k]);
            }
        }
    }
    #pragma unroll
    for (int k = 0; k < 9; ++k) bnum[((size_t)bg * 9 + k) * NC + c] = acc[k];
}

// ---- K5: gather paint sums -> per-superpixel channel means (f32) ----------
__global__ __launch_bounds__(64) void k_means_(const double* __restrict__ bnum,
                                               const double* __restrict__ bden,
                                               float* __restrict__ means) {
    int s = blockIdx.x, c = threadIdx.x;
    int sy = s / NSW, sx = s % NSW;
    double num = 0.0, den = 0.0;
    #pragma unroll
    for (int k = 0; k < 9; ++k) {
        int by2 = sy - (k / 3 - 1), bx2 = sx - (k % 3 - 1);
        if (by2 >= 0 && by2 < NSH && bx2 >= 0 && bx2 < NSW) {
            int b2 = by2 * NSW + bx2;
            #pragma unroll
            for (int g = 0; g < 4; ++g) {
                int bg = b2 * 4 + g;
                num += bnum[((size_t)bg * 9 + k) * NC + c];
                den += bden[(size_t)bg * 9 + k];
            }
        }
    }
    means[s * NC + c] = (float)(num / fmax(den, 1.0));
}

// ---- K6: paint out[c][p] = means[lab[p]][c]; 4 px x 4 ch per thread -------
__global__ __launch_bounds__(256) void k_paint(const int* __restrict__ labels,
                                               const float* __restrict__ means,
                                               float* __restrict__ out) {
    int p0 = (blockIdx.x * 256 + threadIdx.x) * 4;
    int4 lb = *(const int4*)&labels[p0];
    int c0 = blockIdx.y * 4;
    #pragma unroll
    for (int j = 0; j < 4; ++j) {
        int c = c0 + j;
        float4 o;
        o.x = means[lb.x * NC + c];
        o.y = means[lb.y * NC + c];
        o.z = means[lb.z * NC + c];
        o.w = means[lb.w * NC + c];
        *(float4*)&out[(size_t)c * HWP + p0] = o;
    }
}

extern "C" void kernel_launch(void* const* d_in, const int* in_sizes, int n_in,
                              void* d_out, int out_size, void* d_ws, size_t ws_size,
                              hipStream_t stream) {
    const float* x = (const float*)d_in[0];
    float* out = (float*)d_out;
    char* ws = (char*)d_ws;
    char* od = (char*)d_out;

    constexpr size_t CENTP_B = (size_t)NBG * NC * 8;      // 1179648
    constexpr size_t CENT_B  = (size_t)NS * NC * 8;       // 294912 (x2)
    constexpr size_t CNRM_B  = (size_t)NS * 8;            // 4608   (x2)
    constexpr size_t BNUM_B  = (size_t)NBG * 9 * NC * 8;  // 10616832
    constexpr size_t BDEN_B  = (size_t)NBG * 9 * 8;       // 165888
    constexpr size_t LAB_B   = (size_t)HWP * 4;           // 589824
    constexpr size_t MEANS_B = (size_t)NS * NC * 4;       // 147456
    constexpr size_t T_PAINT = LAB_B + MEANS_B;           // must live in ws
    constexpr size_t T_CENT  = T_PAINT + 2 * (CENT_B + CNRM_B);
    constexpr size_t T_ALL   = T_CENT + CENTP_B + BNUM_B + BDEN_B;

    int* labels = (int*)ws;
    float* means = (float*)(ws + LAB_B);
    double *centA, *centB, *cnormA, *cnormB, *centp, *bnum, *bden;
    if (ws_size >= T_ALL) {
        centA  = (double*)(ws + T_PAINT);
        centB  = (double*)(ws + T_PAINT + CENT_B);
        cnormA = (double*)(ws + T_PAINT + 2 * CENT_B);
        cnormB = (double*)(ws + T_PAINT + 2 * CENT_B + CNRM_B);
        centp  = (double*)(ws + T_CENT);
        bnum   = (double*)(ws + T_CENT + CENTP_B);
        bden   = (double*)(ws + T_CENT + CENTP_B + BNUM_B);
    } else if (ws_size >= T_CENT) {
        centA  = (double*)(ws + T_PAINT);
        centB  = (double*)(ws + T_PAINT + CENT_B);
        cnormA = (double*)(ws + T_PAINT + 2 * CENT_B);
        cnormB = (double*)(ws + T_PAINT + 2 * CENT_B + CNRM_B);
        centp  = (double*)od;
        bnum   = (double*)(od + CENTP_B);
        bden   = (double*)(od + CENTP_B + BNUM_B);
    } else {
        centp  = (double*)od;
        bnum   = (double*)(od + CENTP_B);
        bden   = (double*)(od + CENTP_B + BNUM_B);
        centA  = (double*)(od + CENTP_B + BNUM_B + BDEN_B);
        centB  = (double*)(od + CENTP_B + BNUM_B + BDEN_B + CENT_B);
        cnormA = (double*)(od + CENTP_B + BNUM_B + BDEN_B + 2 * CENT_B);
        cnormB = (double*)(od + CENTP_B + BNUM_B + BDEN_B + 2 * CENT_B + CNRM_B);
    }
    // all d_out-resident scratch is consumed before k_paint overwrites d_out

    k_cent_part<<<NBG, 256, 0, stream>>>(x, centp);
    k_cent_red<<<NS, 64, 0, stream>>>(centp, centA, cnormA);
    k_iter<<<NBG, 64, 0, stream>>>(x, centA, cnormA, bnum, bden);
    k_gather_cent<<<NS, 64, 0, stream>>>(bnum, bden, centB, cnormB);
    k_iter<<<NBG, 64, 0, stream>>>(x, centB, cnormB, bnum, bden);
    k_gather_cent<<<NS, 64, 0, stream>>>(bnum, bden, centA, cnormA);
    k_final<<<NBG, 64, 0, stream>>>(x, centA, cnormA, labels, bnum, bden);
    k_means_<<<NS, 64, 0, stream>>>(bnum, bden, means);
    k_paint<<<dim3(HWP / 1024, NC / 4), 256, 0, stream>>>(labels, means, out);
}